// Round 9
// baseline (242.818 us; speedup 1.0000x reference)
//
#include <hip/hip_runtime.h>

#define BTOT 4096
#define TS 32

typedef __attribute__((ext_vector_type(8))) short bfrag;   // 8 bf16, 16 B
typedef __attribute__((ext_vector_type(4))) float f32x4;

#define S1 (-1.44269504089f)   // -log2(e)
#define S2 (-2.88539008178f)   // -2*log2(e)

__device__ __forceinline__ short f2bf(float f){
  union { float f; unsigned u; } v; v.f = f;
  unsigned r = v.u + 0x7FFFu + ((v.u >> 16) & 1u);   // RNE
  return (short)(r >> 16);
}
__device__ __forceinline__ float bf2f(short s){
  union { unsigned u; float f; } v; v.u = ((unsigned)(unsigned short)s) << 16; return v.f;
}

struct LstmP {
  const float* x[6];
  const float* wih[6];
  const float* whh[6];
  const float* bias[6];
  float* hout;        // [6][BTOT][64] fp32
};

struct EpiP {
  const float* hout;
  const float* s2;
  const float* w03[2]; const float* b03[2];
  const float* w1[2];  const float* b1[2];
  const float* w2[2];  const float* b2[2];
  float* out;
};

// SINGLE-WAVE block: run = blockIdx.y, 16 batch rows, 64 threads = 1 wave.
// The wave owns ALL 4 gates x ALL 64 columns: 32 B-frags (128 VGPR),
// 16 cells/lane, 32 MFMA/step. h recirculates through this wave's private
// LDS (plain bf16, double-buffered) with compiler lgkmcnt waits only —
// NO barrier in the recurrence loop, no inter-wave coupling.
// Weights pre-scaled by -log2e (i,f,o) / -2log2e (g): exp = bare v_exp_f32.
//   c' = [c*(1+eg)(1+ei) + (1-eg)(1+ef)] * rcp((1+ef)(1+eg)(1+ei))
//   h  = (1-ec) * rcp((1+ec)(1+eo)),  ec = exp2(S2*c')
__global__ __launch_bounds__(64) void lstm6(LstmP p){
  const int run = blockIdx.y;
  const int b0 = blockIdx.x * 16;
  const int lane = threadIdx.x;
  const int i16 = lane & 15, q = lane >> 4;

  __shared__ bfrag hb[2][16*9];   // [parity][row*9frags]; row stride 72 shorts
  __shared__ float xs[16*33];     // [m][s], stride 33 (pad)

  const float* __restrict__ whh = p.whh[run];

  // B-fragments (plain bf16, pre-scaled): [gate][coltile][kfrag] = 128 VGPR
  bfrag B[4][4][2];
  float wihv[4][4], bv[4][4];
#pragma unroll
  for (int g = 0; g < 4; ++g){
    const float sg = (g == 2) ? S2 : S1;
#pragma unroll
    for (int jt = 0; jt < 4; ++jt){
      const int n = 64*g + 16*jt + i16;          // gate row index
      const float* wr = whh + n*64;
#pragma unroll
      for (int kf = 0; kf < 2; ++kf){
        const float* src = wr + 32*kf + 8*q;
        bfrag bb;
#pragma unroll
        for (int j = 0; j < 8; ++j) bb[j] = f2bf(src[j] * sg);
        B[g][jt][kf] = bb;
      }
      wihv[g][jt] = p.wih[run][n] * sg;
      bv[g][jt]   = p.bias[run][n] * sg;
    }
  }
  {
    const float* x = p.x[run] + (size_t)b0 * TS;
    for (int i = lane; i < 16*TS; i += 64) xs[(i>>5)*33 + (i&31)] = x[i];
    int* hz = (int*)&hb[0][0];            // zero parity-0 plane (576 dwords)
    for (int i = lane; i < 576; i += 64) hz[i] = 0;
  }
  __syncthreads();   // single wave: ~free; orders staging before loop

  float c[4][4];     // [jt][r]
#pragma unroll
  for (int jt = 0; jt < 4; ++jt)
#pragma unroll
    for (int r = 0; r < 4; ++r) c[jt][r] = 0.0f;
  float hlast[4][4];

  for (int s = 0; s < TS; ++s){
    const bfrag* hh = hb[s & 1];
    short* wh = (short*)hb[(s+1) & 1];
    const int af = i16*9 + q;
    bfrag ah0 = hh[af];          // A: m=i16, k=8q+j  (k 0..31)
    bfrag ah1 = hh[af + 4];      //                   (k 32..63)
    float xm[4];
#pragma unroll
    for (int r = 0; r < 4; ++r) xm[r] = xs[(4*q + r)*33 + s];

#pragma unroll
    for (int jt = 0; jt < 4; ++jt){
      f32x4 acc[4];
#pragma unroll
      for (int g = 0; g < 4; ++g){
#pragma unroll
        for (int r = 0; r < 4; ++r) acc[g][r] = fmaf(xm[r], wihv[g][jt], bv[g][jt]);
        acc[g] = __builtin_amdgcn_mfma_f32_16x16x32_bf16(ah0, B[g][jt][0], acc[g], 0,0,0);
        acc[g] = __builtin_amdgcn_mfma_f32_16x16x32_bf16(ah1, B[g][jt][1], acc[g], 0,0,0);
      }
#pragma unroll
      for (int r = 0; r < 4; ++r){
        float ei = __builtin_amdgcn_exp2f(acc[0][r]);
        float ef = __builtin_amdgcn_exp2f(acc[1][r]);
        float eg = __builtin_amdgcn_exp2f(acc[2][r]);
        float eo = __builtin_amdgcn_exp2f(acc[3][r]);
        float pf = 1.0f + ef;
        float D1 = (1.0f + eg) * (1.0f + ei);
        float num = fmaf(c[jt][r], D1, (1.0f - eg) * pf);
        float cc = num * __builtin_amdgcn_rcpf(pf * D1);
        c[jt][r] = cc;
        float ec = __builtin_amdgcn_exp2f(cc * S2);
        float hv = (1.0f - ec) * __builtin_amdgcn_rcpf((1.0f + ec) * (1.0f + eo));
        hlast[jt][r] = hv;
        wh[(4*q + r)*72 + 16*jt + i16] = f2bf(hv);
      }
    }
    // no barrier: same wave reads hb next step; compiler emits lgkmcnt wait
  }

#pragma unroll
  for (int jt = 0; jt < 4; ++jt)
#pragma unroll
    for (int r = 0; r < 4; ++r){
      int m = 4*q + r, j = 16*jt + i16;
      p.hout[((size_t)run*BTOT + b0 + m)*64 + j] = hlast[jt][r];
    }
}

// Epilogue: 16 batch / block, grid (256, 2). Layer1 (256->64) split-bf16 MFMA,
// layer2 (64->6) fp32 VALU, log_softmax for i-branch. (R5/R8 version, ~free.)
__global__ __launch_bounds__(256) void epilogue(EpiP p){
  const int br = blockIdx.y;
  const int b0 = blockIdx.x * 16;
  const int t = threadIdx.x;
  const int wave = t >> 6, lane = t & 63;
  const int i16 = lane & 15, q = lane >> 4;

  __shared__ bfrag hqv_hi[16*33], hqv_lo[16*33];   // [m][k], stride 33 frags
  __shared__ float qv[16*66];                       // layer1 out, stride 66
  __shared__ float iv[16][6];

  const float* hbase = p.hout + (size_t)br*3*BTOT*64;
  {
    short4* dh = (short4*)hqv_hi;
    short4* dl = (short4*)hqv_lo;
    for (int i = t; i < 768; i += 256){
      int run = i >> 8, ii = i & 255;
      int e = ii >> 4, j4 = ii & 15;
      float4 v = *(const float4*)(hbase + ((size_t)run*BTOT + b0 + e)*64 + j4*4);
      short4 h, l;
      short x0 = f2bf(v.x); h.x = x0; l.x = f2bf(v.x - bf2f(x0));
      short x1 = f2bf(v.y); h.y = x1; l.y = f2bf(v.y - bf2f(x1));
      short x2 = f2bf(v.z); h.z = x2; l.z = f2bf(v.z - bf2f(x2));
      short x3 = f2bf(v.w); h.w = x3; l.w = f2bf(v.w - bf2f(x3));
      int o4 = e*66 + run*16 + j4;               // short4 units
      dh[o4] = h;
      dl[o4] = l;
    }
  }
  {
    short* sh = (short*)hqv_hi;
    short* sl = (short*)hqv_lo;
    const float* w03 = p.w03[br];
    const float* b03 = p.b03[br];
    for (int i = t; i < 1024; i += 256){
      int e = i >> 6, jj = i & 63;
      const float* s2r = p.s2 + (size_t)(b0 + e)*3;
      float v = fmaf(s2r[0], w03[jj*3+0],
                fmaf(s2r[1], w03[jj*3+1],
                fmaf(s2r[2], w03[jj*3+2], b03[jj])));
      v = fmaxf(v, 0.0f);
      int off = e*264 + 192 + jj;
      short hi = f2bf(v);
      sh[off] = hi;
      sl[off] = f2bf(v - bf2f(hi));
    }
  }
  __syncthreads();

  // layer1: wave owns n-tile = wave -> output col n = 16*wave + i16
  {
    const int n = 16*wave + i16;
    const float* w1r = p.w1[br] + (size_t)n*256;
    f32x4 acc;
    { float bb = p.b1[br][n]; acc[0]=bb; acc[1]=bb; acc[2]=bb; acc[3]=bb; }
#pragma unroll
    for (int ks = 0; ks < 8; ++ks){
      bfrag ah = hqv_hi[i16*33 + 4*ks + q];
      bfrag al = hqv_lo[i16*33 + 4*ks + q];
      const float* src = w1r + 32*ks + 8*q;
      bfrag bh, bl;
#pragma unroll
      for (int j = 0; j < 8; ++j){
        float f = src[j];
        short hi = f2bf(f);
        bh[j] = hi;
        bl[j] = f2bf(f - bf2f(hi));
      }
      acc = __builtin_amdgcn_mfma_f32_16x16x32_bf16(ah, bh, acc, 0,0,0);
      acc = __builtin_amdgcn_mfma_f32_16x16x32_bf16(al, bh, acc, 0,0,0);
      acc = __builtin_amdgcn_mfma_f32_16x16x32_bf16(ah, bl, acc, 0,0,0);
    }
#pragma unroll
    for (int r = 0; r < 4; ++r)
      qv[(4*q + r)*66 + n] = fmaxf(acc[r], 0.0f);
  }
  __syncthreads();

  if (t < 96){
    int e = t / 6, a = t % 6;
    const float* w2r = p.w2[br] + a*64;
    const float* qe = qv + e*66;
    float acc2 = p.b2[br][a];
#pragma unroll 8
    for (int k = 0; k < 64; ++k) acc2 = fmaf(qe[k], w2r[k], acc2);
    int b = b0 + e;
    if (br == 0){
      p.out[(size_t)b*6 + a] = acc2;                       // q head
    } else {
      float v = fmaxf(acc2, 0.0f);
      iv[e][a] = v;
      p.out[(size_t)2*BTOT*6 + (size_t)b*6 + a] = v;       // i (third output)
    }
  }
  __syncthreads();
  if (br == 1 && t < 16){
    float m = iv[t][0];
    for (int a2 = 1; a2 < 6; ++a2) m = fmaxf(m, iv[t][a2]);
    float ss = 0.0f;
    for (int a2 = 0; a2 < 6; ++a2) ss += __expf(iv[t][a2] - m);
    float ls = __logf(ss);
    int b = b0 + t;
    for (int a2 = 0; a2 < 6; ++a2)
      p.out[(size_t)BTOT*6 + (size_t)b*6 + a2] = iv[t][a2] - m - ls;
  }
}

extern "C" void kernel_launch(void* const* d_in, const int* in_sizes, int n_in,
                              void* d_out, int out_size, void* d_ws, size_t ws_size,
                              hipStream_t stream) {
  const float* x0 = (const float*)d_in[0];
  const float* x1 = (const float*)d_in[1];
  const float* x2 = (const float*)d_in[2];
  const float* s2 = (const float*)d_in[3];

  LstmP lp;
  lp.x[0]=x0; lp.x[1]=x1; lp.x[2]=x2; lp.x[3]=x0; lp.x[4]=x1; lp.x[5]=x2;
  const int wbase[6] = {4, 7, 7, 10, 13, 16};   // q00, q01, q01, i00, i01, i02
  for (int r = 0; r < 6; ++r){
    lp.wih[r]  = (const float*)d_in[wbase[r]+0];
    lp.whh[r]  = (const float*)d_in[wbase[r]+1];
    lp.bias[r] = (const float*)d_in[wbase[r]+2];
  }
  lp.hout = (float*)d_ws;   // 6*4096*64 fp32 = 6.29 MB

  lstm6<<<dim3(BTOT/16, 6), 64, 0, stream>>>(lp);

  EpiP ep;
  ep.hout = (const float*)d_ws;
  ep.s2 = s2;
  ep.w03[0]=(const float*)d_in[19]; ep.b03[0]=(const float*)d_in[20];
  ep.w1 [0]=(const float*)d_in[21]; ep.b1 [0]=(const float*)d_in[22];
  ep.w2 [0]=(const float*)d_in[23]; ep.b2 [0]=(const float*)d_in[24];
  ep.w03[1]=(const float*)d_in[25]; ep.b03[1]=(const float*)d_in[26];
  ep.w1 [1]=(const float*)d_in[27]; ep.b1 [1]=(const float*)d_in[28];
  ep.w2 [1]=(const float*)d_in[29]; ep.b2 [1]=(const float*)d_in[30];
  ep.out = (float*)d_out;

  epilogue<<<dim3(BTOT/16, 2), 256, 0, stream>>>(ep);
}

// Round 11
// 182.223 us; speedup vs baseline: 1.3325x; 1.3325x over previous
//
#include <hip/hip_runtime.h>

#define BTOT 4096
#define TS 32

typedef __attribute__((ext_vector_type(8))) short bfrag;   // 8 bf16, 16 B
typedef __attribute__((ext_vector_type(4))) float f32x4;

#define S1 (-1.44269504089f)   // -log2(e)
#define S2 (-2.88539008178f)   // -2*log2(e)

__device__ __forceinline__ short f2bf(float f){
  union { float f; unsigned u; } v; v.f = f;
  unsigned r = v.u + 0x7FFFu + ((v.u >> 16) & 1u);   // RNE
  return (short)(r >> 16);
}
__device__ __forceinline__ float bf2f(short s){
  union { unsigned u; float f; } v; v.u = ((unsigned)(unsigned short)s) << 16; return v.f;
}
__device__ __forceinline__ f32x4 exp2v(f32x4 a){
  f32x4 r;
  r[0] = __builtin_amdgcn_exp2f(a[0]);
  r[1] = __builtin_amdgcn_exp2f(a[1]);
  r[2] = __builtin_amdgcn_exp2f(a[2]);
  r[3] = __builtin_amdgcn_exp2f(a[3]);
  return r;
}
__device__ __forceinline__ f32x4 rcpv(f32x4 a){
  f32x4 r;
  r[0] = __builtin_amdgcn_rcpf(a[0]);
  r[1] = __builtin_amdgcn_rcpf(a[1]);
  r[2] = __builtin_amdgcn_rcpf(a[2]);
  r[3] = __builtin_amdgcn_rcpf(a[3]);
  return r;
}

struct LstmP {
  const float* x[6];
  const float* wih[6];
  const float* whh[6];
  const float* bias[6];
  float* hout;        // [6][BTOT][64] fp32
};

struct EpiP {
  const float* hout;
  const float* s2;
  const float* w03[2]; const float* b03[2];
  const float* w1[2];  const float* b1[2];
  const float* w2[2];  const float* b2[2];
  float* out;
};

// Block: run = blockIdx.y, 16 batch rows, 4 waves (256 thr). (R8 topology —
// measured optimum: 6144 waves, VGPR ~56, 1 barrier/step.)
// Wave w owns ALL 4 gates for cols j = 16w + i16: 8 plain-bf16 B-frags,
// 4 cells/lane, 8 MFMA/step/wave.
// Gate math is expressed on 4-wide float vectors so the compiler can emit
// CDNA packed fp32 (v_pk_fma_f32 etc., 2x issue rate); exp/rcp stay scalar.
// Weights pre-scaled by -log2e (i,f,o) / -2log2e (g): exp = bare v_exp_f32.
//   c' = [c*(1+eg)(1+ei) + (1-eg)(1+ef)] * rcp((1+ef)(1+eg)(1+ei))
//   h  = (1-ec) * rcp((1+ec)(1+eo)),  ec = exp2(S2*c')
__global__ __launch_bounds__(256, 4) void lstm6(LstmP p){
  const int run = blockIdx.y;
  const int b0 = blockIdx.x * 16;
  const int t = threadIdx.x;
  const int w = t >> 6, lane = t & 63;
  const int i16 = lane & 15, q = lane >> 4;

  __shared__ bfrag hb[2][16*9];   // [parity][row*9frags]; row stride 72 shorts
  __shared__ float xsT[TS*20];    // TRANSPOSED [s][m], stride 20 (80B, 16B-aligned)

  const float* __restrict__ whh = p.whh[run];

  // B-fragments (plain bf16, pre-scaled): [gate][kfrag] = 8 frags (32 VGPR)
  bfrag B[4][2];
  float wihv[4], bv[4];
#pragma unroll
  for (int g = 0; g < 4; ++g){
    const float sg = (g == 2) ? S2 : S1;
    const int n = 64*g + 16*w + i16;             // gate row index
    const float* wr = whh + n*64;
#pragma unroll
    for (int kf = 0; kf < 2; ++kf){
      const float* src = wr + 32*kf + 8*q;
      bfrag bb;
#pragma unroll
      for (int j = 0; j < 8; ++j) bb[j] = f2bf(src[j] * sg);
      B[g][kf] = bb;
    }
    wihv[g] = p.wih[run][n] * sg;
    bv[g]   = p.bias[run][n] * sg;
  }
  {
    const float* x = p.x[run] + (size_t)b0 * TS;
    for (int i = t; i < 16*TS; i += 256){
      int m = i & 15, s = i >> 4;
      xsT[s*20 + m] = x[m*TS + s];
    }
    int* hz = (int*)&hb[0][0];            // zero parity-0 plane (576 dwords)
    for (int i = t; i < 576; i += 256) hz[i] = 0;
  }
  __syncthreads();

  f32x4 c4 = {0.f, 0.f, 0.f, 0.f};
  f32x4 hlast;

  for (int s = 0; s < TS; ++s){
    const bfrag* hh = hb[s & 1];
    short* wh = (short*)hb[(s+1) & 1];
    const int af = i16*9 + q;
    bfrag ah0 = hh[af];          // A: m=i16, k=8q+j  (k 0..31)
    bfrag ah1 = hh[af + 4];      //                   (k 32..63)
    f32x4 xm4 = *(const f32x4*)(xsT + s*20 + 4*q);   // rows 4q..4q+3, one b128

    f32x4 acc[4];
#pragma unroll
    for (int g = 0; g < 4; ++g){
      acc[g] = xm4 * wihv[g] + bv[g];               // packed fma (splat)
      acc[g] = __builtin_amdgcn_mfma_f32_16x16x32_bf16(ah0, B[g][0], acc[g], 0,0,0);
      acc[g] = __builtin_amdgcn_mfma_f32_16x16x32_bf16(ah1, B[g][1], acc[g], 0,0,0);
    }
    f32x4 ei = exp2v(acc[0]);
    f32x4 ef = exp2v(acc[1]);
    f32x4 eg = exp2v(acc[2]);
    f32x4 eo = exp2v(acc[3]);
    f32x4 pf = 1.0f + ef;
    f32x4 D1 = (1.0f + eg) * (1.0f + ei);
    f32x4 num = __builtin_elementwise_fma(c4, D1, (1.0f - eg) * pf);
    f32x4 cc = num * rcpv(pf * D1);
    c4 = cc;
    f32x4 ec = exp2v(cc * S2);
    f32x4 hv = (1.0f - ec) * rcpv((1.0f + ec) * (1.0f + eo));
    hlast = hv;
    const int wbase = (4*q)*72 + 16*w + i16;
#pragma unroll
    for (int r = 0; r < 4; ++r)
      wh[wbase + r*72] = f2bf(hv[r]);
    __syncthreads();
  }

#pragma unroll
  for (int r = 0; r < 4; ++r){
    int m = 4*q + r, j = 16*w + i16;
    p.hout[((size_t)run*BTOT + b0 + m)*64 + j] = hlast[r];
  }
}

// Epilogue: 16 batch / block, grid (256, 2). Layer1 (256->64) split-bf16 MFMA,
// layer2 (64->6) fp32 VALU, log_softmax for i-branch. (R8 version, ~free.)
__global__ __launch_bounds__(256) void epilogue(EpiP p){
  const int br = blockIdx.y;
  const int b0 = blockIdx.x * 16;
  const int t = threadIdx.x;
  const int wave = t >> 6, lane = t & 63;
  const int i16 = lane & 15, q = lane >> 4;

  __shared__ bfrag hqv_hi[16*33], hqv_lo[16*33];   // [m][k], stride 33 frags
  __shared__ float qv[16*66];                       // layer1 out, stride 66
  __shared__ float iv[16][6];

  const float* hbase = p.hout + (size_t)br*3*BTOT*64;
  {
    short4* dh = (short4*)hqv_hi;
    short4* dl = (short4*)hqv_lo;
    for (int i = t; i < 768; i += 256){
      int run = i >> 8, ii = i & 255;
      int e = ii >> 4, j4 = ii & 15;
      float4 v = *(const float4*)(hbase + ((size_t)run*BTOT + b0 + e)*64 + j4*4);
      short4 h, l;
      short x0 = f2bf(v.x); h.x = x0; l.x = f2bf(v.x - bf2f(x0));
      short x1 = f2bf(v.y); h.y = x1; l.y = f2bf(v.y - bf2f(x1));
      short x2 = f2bf(v.z); h.z = x2; l.z = f2bf(v.z - bf2f(x2));
      short x3 = f2bf(v.w); h.w = x3; l.w = f2bf(v.w - bf2f(x3));
      int o4 = e*66 + run*16 + j4;               // short4 units
      dh[o4] = h;
      dl[o4] = l;
    }
  }
  {
    short* sh = (short*)hqv_hi;
    short* sl = (short*)hqv_lo;
    const float* w03 = p.w03[br];
    const float* b03 = p.b03[br];
    for (int i = t; i < 1024; i += 256){
      int e = i >> 6, jj = i & 63;
      const float* s2r = p.s2 + (size_t)(b0 + e)*3;
      float v = fmaf(s2r[0], w03[jj*3+0],
                fmaf(s2r[1], w03[jj*3+1],
                fmaf(s2r[2], w03[jj*3+2], b03[jj])));
      v = fmaxf(v, 0.0f);
      int off = e*264 + 192 + jj;
      short hi = f2bf(v);
      sh[off] = hi;
      sl[off] = f2bf(v - bf2f(hi));
    }
  }
  __syncthreads();

  // layer1: wave owns n-tile = wave -> output col n = 16*wave + i16
  {
    const int n = 16*wave + i16;
    const float* w1r = p.w1[br] + (size_t)n*256;
    f32x4 acc;
    { float bb = p.b1[br][n]; acc[0]=bb; acc[1]=bb; acc[2]=bb; acc[3]=bb; }
#pragma unroll
    for (int ks = 0; ks < 8; ++ks){
      bfrag ah = hqv_hi[i16*33 + 4*ks + q];
      bfrag al = hqv_lo[i16*33 + 4*ks + q];
      const float* src = w1r + 32*ks + 8*q;
      bfrag bh, bl;
#pragma unroll
      for (int j = 0; j < 8; ++j){
        float f = src[j];
        short hi = f2bf(f);
        bh[j] = hi;
        bl[j] = f2bf(f - bf2f(hi));
      }
      acc = __builtin_amdgcn_mfma_f32_16x16x32_bf16(ah, bh, acc, 0,0,0);
      acc = __builtin_amdgcn_mfma_f32_16x16x32_bf16(al, bh, acc, 0,0,0);
      acc = __builtin_amdgcn_mfma_f32_16x16x32_bf16(ah, bl, acc, 0,0,0);
    }
#pragma unroll
    for (int r = 0; r < 4; ++r)
      qv[(4*q + r)*66 + n] = fmaxf(acc[r], 0.0f);
  }
  __syncthreads();

  if (t < 96){
    int e = t / 6, a = t % 6;
    const float* w2r = p.w2[br] + a*64;
    const float* qe = qv + e*66;
    float acc2 = p.b2[br][a];
#pragma unroll 8
    for (int k = 0; k < 64; ++k) acc2 = fmaf(qe[k], w2r[k], acc2);
    int b = b0 + e;
    if (br == 0){
      p.out[(size_t)b*6 + a] = acc2;                       // q head
    } else {
      float v = fmaxf(acc2, 0.0f);
      iv[e][a] = v;
      p.out[(size_t)2*BTOT*6 + (size_t)b*6 + a] = v;       // i (third output)
    }
  }
  __syncthreads();
  if (br == 1 && t < 16){
    float m = iv[t][0];
    for (int a2 = 1; a2 < 6; ++a2) m = fmaxf(m, iv[t][a2]);
    float ss = 0.0f;
    for (int a2 = 0; a2 < 6; ++a2) ss += __expf(iv[t][a2] - m);
    float ls = __logf(ss);
    int b = b0 + t;
    for (int a2 = 0; a2 < 6; ++a2)
      p.out[(size_t)BTOT*6 + (size_t)b*6 + a2] = iv[t][a2] - m - ls;
  }
}

extern "C" void kernel_launch(void* const* d_in, const int* in_sizes, int n_in,
                              void* d_out, int out_size, void* d_ws, size_t ws_size,
                              hipStream_t stream) {
  const float* x0 = (const float*)d_in[0];
  const float* x1 = (const float*)d_in[1];
  const float* x2 = (const float*)d_in[2];
  const float* s2 = (const float*)d_in[3];

  LstmP lp;
  lp.x[0]=x0; lp.x[1]=x1; lp.x[2]=x2; lp.x[3]=x0; lp.x[4]=x1; lp.x[5]=x2;
  const int wbase[6] = {4, 7, 7, 10, 13, 16};   // q00, q01, q01, i00, i01, i02
  for (int r = 0; r < 6; ++r){
    lp.wih[r]  = (const float*)d_in[wbase[r]+0];
    lp.whh[r]  = (const float*)d_in[wbase[r]+1];
    lp.bias[r] = (const float*)d_in[wbase[r]+2];
  }
  lp.hout = (float*)d_ws;   // 6*4096*64 fp32 = 6.29 MB

  lstm6<<<dim3(BTOT/16, 6), 256, 0, stream>>>(lp);

  EpiP ep;
  ep.hout = (const float*)d_ws;
  ep.s2 = s2;
  ep.w03[0]=(const float*)d_in[19]; ep.b03[0]=(const float*)d_in[20];
  ep.w1 [0]=(const float*)d_in[21]; ep.b1 [0]=(const float*)d_in[22];
  ep.w2 [0]=(const float*)d_in[23]; ep.b2 [0]=(const float*)d_in[24];
  ep.w03[1]=(const float*)d_in[25]; ep.b03[1]=(const float*)d_in[26];
  ep.w1 [1]=(const float*)d_in[27]; ep.b1 [1]=(const float*)d_in[28];
  ep.w2 [1]=(const float*)d_in[29]; ep.b2 [1]=(const float*)d_in[30];
  ep.out = (float*)d_out;

  epilogue<<<dim3(BTOT/16, 2), 256, 0, stream>>>(ep);
}